// Round 3
// baseline (114.019 us; speedup 1.0000x reference)
//
#include <hip/hip_runtime.h>
#include <hip/hip_bf16.h>

typedef __attribute__((ext_vector_type(8))) short s16x8;
typedef __attribute__((ext_vector_type(4))) float fx4;
typedef __attribute__((ext_vector_type(4))) unsigned int u32x4;
typedef unsigned short u16;
typedef unsigned int   u32;
typedef unsigned long long u64;

#define DI __device__ __forceinline__

// B=2, W=512, E=2, P=8, H=1024, NH=16, D=64, T=514
// External I/O: float32. Internal workspace: bf16 (MFMA) .

DI float bf2f(u16 x){ u32 u = ((u32)x)<<16; float f; __builtin_memcpy(&f,&u,4); return f; }
DI u16 f2bf(float f){ u32 u; __builtin_memcpy(&u,&f,4); u = (u + 0x7fffu + ((u>>16)&1u))>>16; return (u16)u; }

DI fx4 mfma_16x16x32_bf16(s16x8 a, s16x8 b, fx4 c){
  return __builtin_amdgcn_mfma_f32_16x16x32_bf16(a,b,c,0,0,0);
}

// ---------------- K00: f32 -> bf16 convert (words / entities) ----------------
__global__ __launch_bounds__(256) void k_cvt(const float* __restrict__ src, u16* __restrict__ dst, int n){
  int i = (blockIdx.x*256 + threadIdx.x)*8;
  if(i < n){
    fx4 a = *(const fx4*)(src+i);
    fx4 b = *(const fx4*)(src+i+4);
    u16 o[8];
    o[0]=f2bf(a[0]); o[1]=f2bf(a[1]); o[2]=f2bf(a[2]); o[3]=f2bf(a[3]);
    o[4]=f2bf(b[0]); o[5]=f2bf(b[1]); o[6]=f2bf(b[2]); o[7]=f2bf(b[3]);
    u32x4 v; __builtin_memcpy(&v,o,16);
    *(u32x4*)(dst+i)=v;
  }
}

// ---------------- K0: transpose 6 weight matrices f32 (k,n) -> bf16 (n,k) ----------------
__global__ __launch_bounds__(256) void k_transpose6(
    const float* __restrict__ s0, const float* __restrict__ s1, const float* __restrict__ s2,
    const float* __restrict__ s3, const float* __restrict__ s4, const float* __restrict__ s5,
    u16* __restrict__ dstbase)
{
  __shared__ __align__(16) u16 tile[64][72];
  int z = blockIdx.z;
  const float* src = (z==0)?s0:(z==1)?s1:(z==2)?s2:(z==3)?s3:(z==4)?s4:s5;
  u16* dst = dstbase + (u64)z*1048576u;
  int kt = blockIdx.x*64, nt = blockIdx.y*64;
  int tid = threadIdx.x;
  #pragma unroll
  for(int it=0; it<2; ++it){
    int c = it*256 + tid;
    int r = c>>3, col = (c&7)*8;
    const float* sp = src + (u64)(kt+r)*1024u + nt + col;
    fx4 a = *(const fx4*)sp;
    fx4 b = *(const fx4*)(sp+4);
    u16 o[8];
    o[0]=f2bf(a[0]); o[1]=f2bf(a[1]); o[2]=f2bf(a[2]); o[3]=f2bf(a[3]);
    o[4]=f2bf(b[0]); o[5]=f2bf(b[1]); o[6]=f2bf(b[2]); o[7]=f2bf(b[3]);
    __builtin_memcpy(&tile[r][col], o, 16);
  }
  __syncthreads();
  #pragma unroll
  for(int it=0; it<2; ++it){
    int c = it*256 + tid;
    int nr = c>>3, kc = (c&7)*8;
    u16 tmp[8];
    #pragma unroll
    for(int j=0;j<8;++j) tmp[j] = tile[kc+j][nr];
    u32x4 v; __builtin_memcpy(&v, tmp, 16);
    *(u32x4*)(dst + (u64)(nt+nr)*1024u + kt + kc) = v;
  }
}

// ---------------- K1: word projections, 128x128 tile MFMA GEMM (bf16 in/out) ----------------
// z=0..2: out layout (B,NH,W,D); z=3: V transposed (B,NH,D,W). Bias is f32.
__global__ __launch_bounds__(256) void k_proj_words(
    const u16* __restrict__ X,
    const u16* __restrict__ wt0, const u16* __restrict__ wt1,
    const u16* __restrict__ wt2, const u16* __restrict__ wt3,
    const float* __restrict__ b0, const float* __restrict__ b1,
    const float* __restrict__ b2, const float* __restrict__ b3,
    u16* __restrict__ o0, u16* __restrict__ o1, u16* __restrict__ o2, u16* __restrict__ o3)
{
  __shared__ __align__(16) u16 XL[128*64];
  __shared__ __align__(16) u16 WL[128*64];
  int z = blockIdx.z;
  const u16* WT  = (z==0)?wt0:(z==1)?wt1:(z==2)?wt2:wt3;
  const float* bias = (z==0)?b0 :(z==1)?b1 :(z==2)?b2 :b3;
  u16* out       = (z==0)?o0 :(z==1)?o1 :(z==2)?o2 :o3;
  int tid = threadIdx.x;
  int nt = blockIdx.x*128, mt = blockIdx.y*128;
  int wv = tid>>6, lane = tid&63, l15 = lane&15, g = lane>>4;
  int wr = (wv>>1)*64, wc = (wv&1)*64;
  fx4 acc[4][4] = {};
  for(int kk=0; kk<1024; kk+=64){
    #pragma unroll
    for(int it=0; it<4; ++it){
      int c = it*256 + tid;
      int r = c>>3, cb = (c&7)*16;
      int scb = cb ^ ((r&7)<<4);   // pre-swizzled global source, linear LDS dest (rule #21)
      *(u32x4*)((char*)XL + r*128 + cb) =
        *(const u32x4*)((const char*)X  + ((u64)(mt+r)*1024u + kk)*2u + scb);
      *(u32x4*)((char*)WL + r*128 + cb) =
        *(const u32x4*)((const char*)WT + ((u64)(nt+r)*1024u + kk)*2u + scb);
    }
    __syncthreads();
    #pragma unroll
    for(int ks=0; ks<2; ++ks){
      s16x8 af[4], bfv[4];
      #pragma unroll
      for(int i=0;i<4;++i){
        int ra = wr + i*16 + l15;
        af[i]  = *(const s16x8*)((const char*)XL + ra*128 + ((ks*64 + g*16) ^ ((ra&7)<<4)));
        int rb = wc + i*16 + l15;
        bfv[i] = *(const s16x8*)((const char*)WL + rb*128 + ((ks*64 + g*16) ^ ((rb&7)<<4)));
      }
      #pragma unroll
      for(int i=0;i<4;++i)
        #pragma unroll
        for(int j=0;j<4;++j)
          acc[i][j] = mfma_16x16x32_bf16(af[i], bfv[j], acc[i][j]);
    }
    __syncthreads();
  }
  bool vmode = (z==3);
  #pragma unroll
  for(int j=0;j<4;++j){
    int n = nt + wc + j*16 + l15;
    float bv = bias[n];
    int h = n>>6, d = n&63;
    #pragma unroll
    for(int i=0;i<4;++i){
      #pragma unroll
      for(int q=0;q<4;++q){
        int m = mt + wr + i*16 + g*4 + q;
        int bb = m>>9, wrow = m&511;
        float v = acc[i][j][q] + bv;
        u64 o = vmode ? (((u64)(bb*16+h)*64u + d)*512u + wrow)
                      : (((u64)(bb*16+h)*512u + wrow)*64u + d);
        out[o] = f2bf(v);
      }
    }
  }
}

// ---------------- K1b: entity projections (M=32) ----------------
// z=0..2: out (B,P,NH,E,D); z=3: V transposed (B,P,NH,D,E). Bias f32.
__global__ __launch_bounds__(256) void k_proj_ents(
    const u16* __restrict__ X,
    const u16* __restrict__ wt0, const u16* __restrict__ wt1,
    const u16* __restrict__ wt2, const u16* __restrict__ wt3,
    const float* __restrict__ b0, const float* __restrict__ b1,
    const float* __restrict__ b2, const float* __restrict__ b3,
    u16* __restrict__ o0, u16* __restrict__ o1, u16* __restrict__ o2, u16* __restrict__ o3)
{
  __shared__ __align__(16) u16 XL[32*64];
  __shared__ __align__(16) u16 WL[128*64];
  int z = blockIdx.z;
  const u16* WT  = (z==0)?wt0:(z==1)?wt1:(z==2)?wt2:wt3;
  const float* bias = (z==0)?b0 :(z==1)?b1 :(z==2)?b2 :b3;
  u16* out       = (z==0)?o0 :(z==1)?o1 :(z==2)?o2 :o3;
  int tid = threadIdx.x;
  int nt = blockIdx.x*128;
  int wv = tid>>6, lane = tid&63, l15 = lane&15, g = lane>>4;
  int wc = wv*32;
  fx4 acc[2][2] = {};
  for(int kk=0; kk<1024; kk+=64){
    {
      int r = tid>>3, cb = (tid&7)*16;
      int scb = cb ^ ((r&7)<<4);
      *(u32x4*)((char*)XL + r*128 + cb) =
        *(const u32x4*)((const char*)X + ((u64)r*1024u + kk)*2u + scb);
    }
    #pragma unroll
    for(int it=0; it<4; ++it){
      int c = it*256 + tid;
      int r = c>>3, cb = (c&7)*16;
      int scb = cb ^ ((r&7)<<4);
      *(u32x4*)((char*)WL + r*128 + cb) =
        *(const u32x4*)((const char*)WT + ((u64)(nt+r)*1024u + kk)*2u + scb);
    }
    __syncthreads();
    #pragma unroll
    for(int ks=0; ks<2; ++ks){
      s16x8 af[2], bfv[2];
      #pragma unroll
      for(int i=0;i<2;++i){
        int ra = i*16 + l15;
        af[i]  = *(const s16x8*)((const char*)XL + ra*128 + ((ks*64 + g*16) ^ ((ra&7)<<4)));
        int rb = wc + i*16 + l15;
        bfv[i] = *(const s16x8*)((const char*)WL + rb*128 + ((ks*64 + g*16) ^ ((rb&7)<<4)));
      }
      #pragma unroll
      for(int i=0;i<2;++i)
        #pragma unroll
        for(int j=0;j<2;++j)
          acc[i][j] = mfma_16x16x32_bf16(af[i], bfv[j], acc[i][j]);
    }
    __syncthreads();
  }
  bool vmode = (z==3);
  #pragma unroll
  for(int j=0;j<2;++j){
    int n = nt + wc + j*16 + l15;
    float bv = bias[n];
    int h = n>>6, d = n&63;
    #pragma unroll
    for(int i=0;i<2;++i){
      #pragma unroll
      for(int q=0;q<4;++q){
        int m = i*16 + g*4 + q;     // 0..31 = ((b*8+p)*2+e)
        int bb = m>>4, p = (m>>1)&7, e = m&1;
        float v = acc[i][j][q] + bv;
        u64 base = ((u64)(bb*8+p)*16u + h);
        u64 o = vmode ? ((base*64u + d)*2u + e)
                      : ((base*2u + e)*64u + d);
        out[o] = f2bf(v);
      }
    }
  }
}

// ---------------- K2: word-query attention ----------------
// One block per (b, h, 64-row q-chunk); 4 waves x 16-row Q tiles.
// Flash loop over 512 word keys computes shared (m, l, N) once; per-p epilogue
// adds the 2 entity keys (online-softmax correction) and writes all 8 p-copies (f32).
__global__ __launch_bounds__(256) void k_word_attn(
    const u16* __restrict__ Qw,  const u16* __restrict__ Q2e,
    const u16* __restrict__ Kw,  const u16* __restrict__ VwT,
    const u16* __restrict__ Ke,  const u16* __restrict__ VeT,
    const float* __restrict__ msk, float* __restrict__ outw)
{
  const float scale = 0.125f;
  __shared__ __align__(16) u16 KL[64*64];
  __shared__ __align__(16) u16 VtL[64*64];
  __shared__ __align__(16) u16 PT[4][64][18];   // per-wave P^T tile (keys x queries), padded
  __shared__ __align__(16) float mask_lds[576];
  __shared__ __align__(16) float obuf[4][16][68];
  int tid = threadIdx.x;
  int qc = blockIdx.x, h = blockIdx.y, b = blockIdx.z;
  int wv = tid>>6, lane = tid&63, l15 = lane&15, g = lane>>4;
  int q0 = qc*64 + wv*16;

  for(int i=tid;i<576;i+=256) mask_lds[i] = (i<514) ? msk[b*514+i] : 0.f;

  // Q tile kept in registers; B-operand layout: lane holds Q[q0+l15][8g+j]
  const u16* Qrow = Qw + ((u64)(b*16+h)*512u + q0 + l15)*64u;
  s16x8 qf0 = *(const s16x8*)(Qrow + g*8);
  s16x8 qf1 = *(const s16x8*)(Qrow + 32 + g*8);

  const char* Kpan = (const char*)(Kw  + (u64)(b*16+h)*512u*64u);
  const char* Vpan = (const char*)(VwT + (u64)(b*16+h)*64u*512u);

  float m_run = -3.0e38f, l_run = 0.f;
  fx4 oacc[4] = {};
  int swz = (l15&7)<<4;

  for(int c=0;c<8;++c){
    #pragma unroll
    for(int it=0; it<2; ++it){
      int cc = it*256 + tid;
      int r = cc>>3, cb = (cc&7)*16;
      int scb = cb ^ ((r&7)<<4);
      *(u32x4*)((char*)KL  + r*128 + cb) = *(const u32x4*)(Kpan + (u64)(c*64+r)*128u + scb);
      *(u32x4*)((char*)VtL + r*128 + cb) = *(const u32x4*)(Vpan + (u64)r*1024u + (u64)c*128u + scb);
    }
    __syncthreads();
    // S^T = K * Q^T : D-layout gives each lane 16 of the 64 chunk keys for query l15
    float sv[4][4];
    #pragma unroll
    for(int s=0;s<4;++s){
      int rk = (s*16 + l15)*128;
      s16x8 ka0 = *(const s16x8*)((const char*)KL + rk + ((g*16) ^ swz));
      s16x8 ka1 = *(const s16x8*)((const char*)KL + rk + ((64 + g*16) ^ swz));
      fx4 st = {0.f,0.f,0.f,0.f};
      st = mfma_16x16x32_bf16(ka0, qf0, st);
      st = mfma_16x16x32_bf16(ka1, qf1, st);
      fx4 mk = *(const fx4*)&mask_lds[c*64 + s*16 + g*4];
      #pragma unroll
      for(int q=0;q<4;++q) sv[s][q] = st[q]*scale + mk[q];
    }
    float cm = -3.0e38f;
    #pragma unroll
    for(int s=0;s<4;++s)
      #pragma unroll
      for(int q=0;q<4;++q) cm = fmaxf(cm, sv[s][q]);
    cm = fmaxf(cm, __shfl_xor(cm, 16, 64));
    cm = fmaxf(cm, __shfl_xor(cm, 32, 64));
    float m_new = fmaxf(m_run, cm);
    float alpha = __expf(m_run - m_new);
    float rs = 0.f;
    #pragma unroll
    for(int s=0;s<4;++s){
      #pragma unroll
      for(int q=0;q<4;++q){
        float e = __expf(sv[s][q] - m_new);
        rs += e;
        PT[wv][s*16 + g*4 + q][l15] = f2bf(e);   // stage P^T[key][query] as bf16
      }
    }
    rs += __shfl_xor(rs, 16, 64);
    rs += __shfl_xor(rs, 32, 64);
    l_run = l_run*alpha + rs;
    m_run = m_new;
    #pragma unroll
    for(int t=0;t<4;++t) oacc[t] *= alpha;
    // drain this wave's ds_writes; PT slice is wave-private
    asm volatile("s_waitcnt lgkmcnt(0)" ::: "memory");
    // O^T += Vt * P^T via 16x16x32: B-frag = 8 contiguous keys per lane from PT
    #pragma unroll
    for(int kh=0;kh<2;++kh){
      u16 ptmp[8];
      #pragma unroll
      for(int j=0;j<8;++j) ptmp[j] = PT[wv][kh*32 + g*8 + j][l15];
      s16x8 pbig; __builtin_memcpy(&pbig, ptmp, 16);
      #pragma unroll
      for(int t=0;t<4;++t){
        int rv = (t*16 + l15)*128;
        s16x8 va = *(const s16x8*)((const char*)VtL + rv + ((kh*64 + g*16) ^ swz));
        oacc[t] = mfma_16x16x32_bf16(va, pbig, oacc[t]);
      }
    }
    __syncthreads();
  }

  // epilogue: per p, fold in the 2 entity keys and write output copy p (f32)
  const u16* Q2row = Q2e + ((u64)(b*16+h)*512u + q0 + l15)*64u + g*16;
  s16x8 q2a = *(const s16x8*)(Q2row);
  s16x8 q2b = *(const s16x8*)(Q2row + 8);
  float q2f[16];
  #pragma unroll
  for(int j=0;j<8;++j){ q2f[j] = bf2f((u16)q2a[j]); q2f[8+j] = bf2f((u16)q2b[j]); }

  int qr = lane>>2, cbo = (lane&3)*16;

  for(int p=0;p<8;++p){
    const u16* KeP = Ke + ((u64)(b*8+p)*16u + h)*128u;
    float s_e[2];
    #pragma unroll
    for(int e=0;e<2;++e){
      const u16* kr = KeP + e*64 + g*16;
      s16x8 k0 = *(const s16x8*)kr;
      s16x8 k1 = *(const s16x8*)(kr+8);
      float dot = 0.f;
      #pragma unroll
      for(int j=0;j<8;++j){
        dot += q2f[j]  * bf2f((u16)k0[j]);
        dot += q2f[8+j]* bf2f((u16)k1[j]);
      }
      dot += __shfl_xor(dot, 16, 64);
      dot += __shfl_xor(dot, 32, 64);
      s_e[e] = dot*scale + mask_lds[512+e];
    }
    float mp = fmaxf(m_run, fmaxf(s_e[0], s_e[1]));
    float al = __expf(m_run - mp);
    float p0 = __expf(s_e[0]-mp), p1 = __expf(s_e[1]-mp);
    float linv = 1.0f/(l_run*al + p0 + p1);
    const u16* VeP = VeT + ((u64)(b*8+p)*16u + h)*128u;
    #pragma unroll
    for(int t=0;t<4;++t){
      #pragma unroll
      for(int q=0;q<4;++q){
        int d = t*16 + g*4 + q;
        u32 vv = *(const u32*)(VeP + d*2);
        float v0 = bf2f((u16)(vv & 0xffffu));
        float v1 = bf2f((u16)(vv >> 16));
        obuf[wv][l15][d] = (oacc[t][q]*al + p0*v0 + p1*v1)*linv;
      }
    }
    asm volatile("s_waitcnt lgkmcnt(0)" ::: "memory");
    // wave-private LDS transpose -> coalesced f32 stores (16 floats / lane)
    float* og = outw + ((u64)(b*8+p)*512u + q0 + qr)*1024u + h*64 + cbo;
    fx4 r0 = *(const fx4*)&obuf[wv][qr][cbo];
    fx4 r1 = *(const fx4*)&obuf[wv][qr][cbo+4];
    fx4 r2 = *(const fx4*)&obuf[wv][qr][cbo+8];
    fx4 r3 = *(const fx4*)&obuf[wv][qr][cbo+12];
    *(fx4*)og     = r0;
    *(fx4*)(og+4) = r1;
    *(fx4*)(og+8) = r2;
    *(fx4*)(og+12)= r3;
  }
}

// ---------------- K3: entity-query rows (2 per (b,p,h)), simple VALU ----------------
__global__ __launch_bounds__(256) void k_ent_attn(
    const u16* __restrict__ Qe2w, const u16* __restrict__ Qe2e,
    const u16* __restrict__ Kw,   const u16* __restrict__ VwT,
    const u16* __restrict__ Ke,   const u16* __restrict__ VeT,
    const float* __restrict__ msk, float* __restrict__ oute)
{
  __shared__ float s_lds[2][516];
  __shared__ float qw_lds[2][64];
  __shared__ float qe_lds[2][64];
  __shared__ float red[2][8];
  int tid = threadIdx.x;
  int bid = blockIdx.x;
  int h = bid&15, p = (bid>>4)&7, b = bid>>7;
  u64 ebase = (u64)(b*8+p)*16u + h;
  if(tid < 128){
    int r = tid>>6, d = tid&63;
    qw_lds[r][d] = bf2f(Qe2w[(ebase*2 + r)*64 + d]);
    qe_lds[r][d] = bf2f(Qe2e[(ebase*2 + r)*64 + d]);
  }
  __syncthreads();
  const u16* Kpan = Kw + (u64)(b*16+h)*512u*64u;
  for(int k=tid;k<512;k+=256){
    const u16* kr = Kpan + (u64)k*64u;
    float d0=0.f, d1=0.f;
    #pragma unroll
    for(int j=0;j<64;j+=8){
      s16x8 kv = *(const s16x8*)(kr+j);
      #pragma unroll
      for(int x=0;x<8;++x){
        float kf = bf2f((u16)kv[x]);
        d0 += qw_lds[0][j+x]*kf;
        d1 += qw_lds[1][j+x]*kf;
      }
    }
    float mk = msk[b*514 + k];
    s_lds[0][k] = d0*0.125f + mk;
    s_lds[1][k] = d1*0.125f + mk;
  }
  if(tid < 4){
    int r = tid>>1, e = tid&1;
    const u16* kr = Ke + (ebase*2 + e)*64;
    float dd = 0.f;
    for(int j=0;j<64;++j) dd += qe_lds[r][j]*bf2f(kr[j]);
    s_lds[r][512+e] = dd*0.125f + msk[b*514 + 512 + e];
  }
  __syncthreads();
  float mx0=-3e38f, mx1=-3e38f;
  for(int k=tid;k<514;k+=256){ mx0=fmaxf(mx0,s_lds[0][k]); mx1=fmaxf(mx1,s_lds[1][k]); }
  #pragma unroll
  for(int off=32; off; off>>=1){
    mx0 = fmaxf(mx0, __shfl_xor(mx0, off, 64));
    mx1 = fmaxf(mx1, __shfl_xor(mx1, off, 64));
  }
  int wv = tid>>6, lane = tid&63;
  if(lane==0){ red[0][wv]=mx0; red[1][wv]=mx1; }
  __syncthreads();
  float m0 = fmaxf(fmaxf(red[0][0],red[0][1]),fmaxf(red[0][2],red[0][3]));
  float m1 = fmaxf(fmaxf(red[1][0],red[1][1]),fmaxf(red[1][2],red[1][3]));
  float sm0=0.f, sm1=0.f;
  for(int k=tid;k<514;k+=256){
    float e0 = __expf(s_lds[0][k]-m0); s_lds[0][k]=e0; sm0+=e0;
    float e1 = __expf(s_lds[1][k]-m1); s_lds[1][k]=e1; sm1+=e1;
  }
  #pragma unroll
  for(int off=32; off; off>>=1){
    sm0 += __shfl_xor(sm0, off, 64);
    sm1 += __shfl_xor(sm1, off, 64);
  }
  if(lane==0){ red[0][4+wv]=sm0; red[1][4+wv]=sm1; }
  __syncthreads();
  float l0 = red[0][4]+red[0][5]+red[0][6]+red[0][7];
  float l1 = red[1][4]+red[1][5]+red[1][6]+red[1][7];
  if(tid < 128){
    int r = tid>>6, d = tid&63;
    const u16* vr = VwT + ((u64)(b*16+h)*64u + d)*512u;
    float acc = 0.f;
    for(int k=0;k<512;k+=8){
      s16x8 vv = *(const s16x8*)(vr+k);
      #pragma unroll
      for(int x=0;x<8;++x) acc += s_lds[r][k+x]*bf2f((u16)vv[x]);
    }
    const u16* ve = VeT + (ebase*64 + d)*2;
    acc += s_lds[r][512]*bf2f(ve[0]) + s_lds[r][513]*bf2f(ve[1]);
    float val = acc / ((r==0)?l0:l1);
    oute[(((u64)(b*8+p)*2u + r)*1024u + h*64 + d)] = val;
  }
}

extern "C" void kernel_launch(void* const* d_in, const int* in_sizes, int n_in,
                              void* d_out, int out_size, void* d_ws, size_t ws_size,
                              hipStream_t stream)
{
  const float* words = (const float*)d_in[0];
  const float* ents  = (const float*)d_in[1];
  const float* amask = (const float*)d_in[2];
  const float* q_w   = (const float*)d_in[3];
  const float* q_b   = (const float*)d_in[4];
  const float* k_w   = (const float*)d_in[5];
  const float* k_b   = (const float*)d_in[6];
  const float* v_w   = (const float*)d_in[7];
  const float* v_b   = (const float*)d_in[8];
  const float* w2e_w = (const float*)d_in[9];
  const float* w2e_b = (const float*)d_in[10];
  const float* e2w_w = (const float*)d_in[11];
  const float* e2w_b = (const float*)d_in[12];
  const float* e2e_w = (const float*)d_in[13];
  const float* e2e_b = (const float*)d_in[14];

  const size_t MW = 1048576;   // elements (u16) per 1024x1024 matrix
  u16* ws16 = (u16*)d_ws;
  if(ws_size < (11*MW + 5*32768)*sizeof(u16)) return;
  u16* WTq   = ws16 + 0*MW;
  u16* WTk   = ws16 + 1*MW;
  u16* WTv   = ws16 + 2*MW;
  u16* WTw2e = ws16 + 3*MW;
  u16* WTe2w = ws16 + 4*MW;
  u16* WTe2e = ws16 + 5*MW;
  u16* Qw    = ws16 + 6*MW;
  u16* Q2e   = ws16 + 7*MW;
  u16* Kwp   = ws16 + 8*MW;
  u16* VwTp  = ws16 + 9*MW;
  u16* Xbf   = ws16 + 10*MW;
  u16* Qe2w  = ws16 + 11*MW;
  u16* Qe2e  = Qe2w + 32768;
  u16* Kep   = Qe2e + 32768;
  u16* VeTp  = Kep + 32768;
  u16* Ebf   = VeTp + 32768;

  dim3 tb(256);
  k_cvt<<<dim3(512), tb, 0, stream>>>(words, Xbf, 1048576);
  k_cvt<<<dim3(16),  tb, 0, stream>>>(ents,  Ebf, 32768);
  k_transpose6<<<dim3(16,16,6), tb, 0, stream>>>(q_w, k_w, v_w, w2e_w, e2w_w, e2e_w, ws16);
  k_proj_words<<<dim3(8,8,4), tb, 0, stream>>>(Xbf,
      WTq, WTw2e, WTk, WTv,  q_b, w2e_b, k_b, v_b,  Qw, Q2e, Kwp, VwTp);
  k_proj_ents<<<dim3(8,1,4), tb, 0, stream>>>(Ebf,
      WTe2w, WTe2e, WTk, WTv,  e2w_b, e2e_b, k_b, v_b,  Qe2w, Qe2e, Kep, VeTp);
  k_word_attn<<<dim3(8,16,2), tb, 0, stream>>>(Qw, Q2e, Kwp, VwTp, Kep, VeTp, amask, (float*)d_out);
  k_ent_attn<<<dim3(256), tb, 0, stream>>>(Qe2w, Qe2e, Kwp, VwTp, Kep, VeTp, amask, (float*)d_out + 8388608u);
}

// Round 4
// 76.384 us; speedup vs baseline: 1.4927x; 1.4927x over previous
//
#include <hip/hip_runtime.h>
#include <hip/hip_bf16.h>

typedef __attribute__((ext_vector_type(8))) short s16x8;
typedef __attribute__((ext_vector_type(4))) float fx4;
typedef __attribute__((ext_vector_type(4))) unsigned int u32x4;
typedef unsigned short u16;
typedef unsigned int   u32;
typedef unsigned long long u64;

#define DI __device__ __forceinline__

// B=2, W=512, E=2, P=8, H=1024, NH=16, D=64, T=514
// External I/O: float32. Internal workspace: bf16 (MFMA).

DI float bf2f(u16 x){ u32 u = ((u32)x)<<16; float f; __builtin_memcpy(&f,&u,4); return f; }
DI u16 f2bf(float f){ u32 u; __builtin_memcpy(&u,&f,4); u = (u + 0x7fffu + ((u>>16)&1u))>>16; return (u16)u; }

DI fx4 mfma_16x16x32_bf16(s16x8 a, s16x8 b, fx4 c){
  return __builtin_amdgcn_mfma_f32_16x16x32_bf16(a,b,c,0,0,0);
}

// ---------------- K_prep: fused weight transpose (f32 k,n -> bf16 n,k) + activations cvt ----
// bx < 1536 : 6 weight transposes (z = bx>>8)
// bx < 2048 : words f32->bf16 (1,048,576 elems)
// bx < 2064 : ents  f32->bf16 (32,768 elems)
__global__ __launch_bounds__(256) void k_prep(
    const float* __restrict__ s0, const float* __restrict__ s1, const float* __restrict__ s2,
    const float* __restrict__ s3, const float* __restrict__ s4, const float* __restrict__ s5,
    u16* __restrict__ dstbase,
    const float* __restrict__ words, u16* __restrict__ Xbf,
    const float* __restrict__ ents,  u16* __restrict__ Ebf)
{
  __shared__ __align__(16) u16 tile[64][72];
  int bx = blockIdx.x, tid = threadIdx.x;
  if(bx < 1536){
    int z = bx>>8, t = bx&255;
    const float* src = (z==0)?s0:(z==1)?s1:(z==2)?s2:(z==3)?s3:(z==4)?s4:s5;
    u16* dst = dstbase + (u64)z*1048576u;
    int kt = (t&15)*64, nt = (t>>4)*64;
    #pragma unroll
    for(int it=0; it<2; ++it){
      int c = it*256 + tid;
      int r = c>>3, col = (c&7)*8;
      const float* sp = src + (u64)(kt+r)*1024u + nt + col;
      fx4 a = *(const fx4*)sp;
      fx4 b = *(const fx4*)(sp+4);
      u16 o[8];
      o[0]=f2bf(a[0]); o[1]=f2bf(a[1]); o[2]=f2bf(a[2]); o[3]=f2bf(a[3]);
      o[4]=f2bf(b[0]); o[5]=f2bf(b[1]); o[6]=f2bf(b[2]); o[7]=f2bf(b[3]);
      __builtin_memcpy(&tile[r][col], o, 16);
    }
    __syncthreads();
    #pragma unroll
    for(int it=0; it<2; ++it){
      int c = it*256 + tid;
      int nr = c>>3, kc = (c&7)*8;
      u16 tmp[8];
      #pragma unroll
      for(int j=0;j<8;++j) tmp[j] = tile[kc+j][nr];
      u32x4 v; __builtin_memcpy(&v, tmp, 16);
      *(u32x4*)(dst + (u64)(nt+nr)*1024u + kt + kc) = v;
    }
  } else {
    const float* src; u16* dst; int i;
    if(bx < 2048){ src = words; dst = Xbf; i = ((bx-1536)*256 + tid)*8; }
    else         { src = ents;  dst = Ebf; i = ((bx-2048)*256 + tid)*8; }
    fx4 a = *(const fx4*)(src+i);
    fx4 b = *(const fx4*)(src+i+4);
    u16 o[8];
    o[0]=f2bf(a[0]); o[1]=f2bf(a[1]); o[2]=f2bf(a[2]); o[3]=f2bf(a[3]);
    o[4]=f2bf(b[0]); o[5]=f2bf(b[1]); o[6]=f2bf(b[2]); o[7]=f2bf(b[3]);
    u32x4 v; __builtin_memcpy(&v,o,16);
    *(u32x4*)(dst+i)=v;
  }
}

// ---------------- K_proj: all 8 projections in one launch ----------------
// grid (8, 9, 4): y<8 -> word GEMM (128x128 tile, T14 reg-prefetch); y==8 -> entity GEMM (M=32).
// word z: 0=Qw 1=Q2e 2=Kw 3=VwT ; ent z: 0=Qe2w 1=Qe2e 2=Ke 3=VeT
__global__ __launch_bounds__(256) void k_proj(
    const u16* __restrict__ Xbf, const u16* __restrict__ Ebf,
    const u16* __restrict__ wtq, const u16* __restrict__ wtw2e,
    const u16* __restrict__ wtk, const u16* __restrict__ wtv,
    const u16* __restrict__ wte2w, const u16* __restrict__ wte2e,
    const float* __restrict__ qb, const float* __restrict__ w2eb,
    const float* __restrict__ kb, const float* __restrict__ vb,
    const float* __restrict__ e2wb, const float* __restrict__ e2eb,
    u16* __restrict__ Qw, u16* __restrict__ Q2e, u16* __restrict__ Kwp, u16* __restrict__ VwTp,
    u16* __restrict__ Qe2w, u16* __restrict__ Qe2e, u16* __restrict__ Kep, u16* __restrict__ VeTp)
{
  __shared__ __align__(16) u16 XL[128*64];
  __shared__ __align__(16) u16 WL[128*64];
  int tid = threadIdx.x;
  int z = blockIdx.z;
  int nt = blockIdx.x*128;
  int wv = tid>>6, lane = tid&63, l15 = lane&15, g = lane>>4;

  if(blockIdx.y < 8){
    // ---- word path ----
    const u16* WT  = (z==0)?wtq:(z==1)?wtw2e:(z==2)?wtk:wtv;
    const float* bias = (z==0)?qb :(z==1)?w2eb :(z==2)?kb :vb;
    u16* out       = (z==0)?Qw :(z==1)?Q2e :(z==2)?Kwp :VwTp;
    int mt = blockIdx.y*128;
    int wr = (wv>>1)*64, wc = (wv&1)*64;
    fx4 acc[4][4] = {};
    u32x4 rx[4], rw[4];
    // prologue: load K-tile 0, write LDS
    #pragma unroll
    for(int it=0; it<4; ++it){
      int c = it*256 + tid;
      int r = c>>3, cb = (c&7)*16, scb = cb ^ ((r&7)<<4);
      rx[it] = *(const u32x4*)((const char*)Xbf + ((u64)(mt+r)*1024u)*2u + scb);
      rw[it] = *(const u32x4*)((const char*)WT  + ((u64)(nt+r)*1024u)*2u + scb);
    }
    #pragma unroll
    for(int it=0; it<4; ++it){
      *(u32x4*)((char*)XL + (it*256+tid)*16) = rx[it];
      *(u32x4*)((char*)WL + (it*256+tid)*16) = rw[it];
    }
    __syncthreads();
    for(int t=0; t<16; ++t){
      int kn = (t+1)*64;
      if(t < 15){
        // T14: issue next tile's global loads now; latency hides under MFMA below
        #pragma unroll
        for(int it=0; it<4; ++it){
          int c = it*256 + tid;
          int r = c>>3, cb = (c&7)*16, scb = cb ^ ((r&7)<<4);
          rx[it] = *(const u32x4*)((const char*)Xbf + ((u64)(mt+r)*1024u + kn)*2u + scb);
          rw[it] = *(const u32x4*)((const char*)WT  + ((u64)(nt+r)*1024u + kn)*2u + scb);
        }
      }
      #pragma unroll
      for(int ks=0; ks<2; ++ks){
        s16x8 af[4], bfv[4];
        #pragma unroll
        for(int i=0;i<4;++i){
          int ra = wr + i*16 + l15;
          af[i]  = *(const s16x8*)((const char*)XL + ra*128 + ((ks*64 + g*16) ^ ((ra&7)<<4)));
          int rb = wc + i*16 + l15;
          bfv[i] = *(const s16x8*)((const char*)WL + rb*128 + ((ks*64 + g*16) ^ ((rb&7)<<4)));
        }
        #pragma unroll
        for(int i=0;i<4;++i)
          #pragma unroll
          for(int j=0;j<4;++j)
            acc[i][j] = mfma_16x16x32_bf16(af[i], bfv[j], acc[i][j]);
      }
      __syncthreads();
      if(t < 15){
        #pragma unroll
        for(int it=0; it<4; ++it){
          *(u32x4*)((char*)XL + (it*256+tid)*16) = rx[it];
          *(u32x4*)((char*)WL + (it*256+tid)*16) = rw[it];
        }
        __syncthreads();
      }
    }
    bool vmode = (z==3);
    #pragma unroll
    for(int j=0;j<4;++j){
      int n = nt + wc + j*16 + l15;
      float bv = bias[n];
      int h = n>>6, d = n&63;
      #pragma unroll
      for(int i=0;i<4;++i){
        #pragma unroll
        for(int q=0;q<4;++q){
          int m = mt + wr + i*16 + g*4 + q;
          int bb = m>>9, wrow = m&511;
          float v = acc[i][j][q] + bv;
          u64 o = vmode ? (((u64)(bb*16+h)*64u + d)*512u + wrow)
                        : (((u64)(bb*16+h)*512u + wrow)*64u + d);
          out[o] = f2bf(v);
        }
      }
    }
  } else {
    // ---- entity path (M=32) ----
    const u16* WT  = (z==0)?wte2w:(z==1)?wte2e:(z==2)?wtk:wtv;
    const float* bias = (z==0)?e2wb :(z==1)?e2eb :(z==2)?kb :vb;
    u16* out       = (z==0)?Qe2w :(z==1)?Qe2e :(z==2)?Kep :VeTp;
    int wc = wv*32;
    fx4 acc[2][2] = {};
    for(int kk=0; kk<1024; kk+=64){
      {
        int r = tid>>3, cb = (tid&7)*16, scb = cb ^ ((r&7)<<4);
        *(u32x4*)((char*)XL + r*128 + cb) =
          *(const u32x4*)((const char*)Ebf + ((u64)r*1024u + kk)*2u + scb);
      }
      #pragma unroll
      for(int it=0; it<4; ++it){
        int c = it*256 + tid;
        int r = c>>3, cb = (c&7)*16, scb = cb ^ ((r&7)<<4);
        *(u32x4*)((char*)WL + r*128 + cb) =
          *(const u32x4*)((const char*)WT + ((u64)(nt+r)*1024u + kk)*2u + scb);
      }
      __syncthreads();
      #pragma unroll
      for(int ks=0; ks<2; ++ks){
        s16x8 af[2], bfv[2];
        #pragma unroll
        for(int i=0;i<2;++i){
          int ra = i*16 + l15;
          af[i]  = *(const s16x8*)((const char*)XL + ra*128 + ((ks*64 + g*16) ^ ((ra&7)<<4)));
          int rb = wc + i*16 + l15;
          bfv[i] = *(const s16x8*)((const char*)WL + rb*128 + ((ks*64 + g*16) ^ ((rb&7)<<4)));
        }
        #pragma unroll
        for(int i=0;i<2;++i)
          #pragma unroll
          for(int j=0;j<2;++j)
            acc[i][j] = mfma_16x16x32_bf16(af[i], bfv[j], acc[i][j]);
      }
      __syncthreads();
    }
    bool vmode = (z==3);
    #pragma unroll
    for(int j=0;j<2;++j){
      int n = nt + wc + j*16 + l15;
      float bv = bias[n];
      int h = n>>6, d = n&63;
      #pragma unroll
      for(int i=0;i<2;++i){
        #pragma unroll
        for(int q=0;q<4;++q){
          int m = i*16 + g*4 + q;     // 0..31 = ((b*8+p)*2+e)
          int bb = m>>4, p = (m>>1)&7, e = m&1;
          float v = acc[i][j][q] + bv;
          u64 base = ((u64)(bb*8+p)*16u + h);
          u64 o = vmode ? ((base*64u + d)*2u + e)
                        : ((base*2u + e)*64u + d);
          out[o] = f2bf(v);
        }
      }
    }
  }
}

// ---------------- K2: word-query attention ----------------
// Block per (b, h, 64-q-chunk); 4 waves x 16-row Q tiles. Flash over 512 word keys
// (T14 chunk prefetch), shared (m,l,N); numerator transposed ONCE, then 8 p-corrections
// as pure VALU + coalesced f32 stores.
__global__ __launch_bounds__(256) void k_word_attn(
    const u16* __restrict__ Qw,  const u16* __restrict__ Q2e,
    const u16* __restrict__ Kw,  const u16* __restrict__ VwT,
    const u16* __restrict__ Ke,  const u16* __restrict__ VeT,
    const float* __restrict__ msk, float* __restrict__ outw)
{
  const float scale = 0.125f;
  __shared__ __align__(16) u16 KL[64*64];
  __shared__ __align__(16) u16 VtL[64*64];
  __shared__ __align__(16) u16 PT[4][64][18];
  __shared__ __align__(16) float mask_lds[576];
  __shared__ __align__(16) float obuf[4][16][68];
  int tid = threadIdx.x;
  int qc = blockIdx.x, h = blockIdx.y, b = blockIdx.z;
  int wv = tid>>6, lane = tid&63, l15 = lane&15, g = lane>>4;
  int q0 = qc*64 + wv*16;

  for(int i=tid;i<576;i+=256) mask_lds[i] = (i<514) ? msk[b*514+i] : 0.f;

  const u16* Qrow = Qw + ((u64)(b*16+h)*512u + q0 + l15)*64u;
  s16x8 qf0 = *(const s16x8*)(Qrow + g*8);
  s16x8 qf1 = *(const s16x8*)(Qrow + 32 + g*8);

  const char* Kpan = (const char*)(Kw  + (u64)(b*16+h)*512u*64u);
  const char* Vpan = (const char*)(VwT + (u64)(b*16+h)*64u*512u);

  float m_run = -3.0e38f, l_run = 0.f;
  fx4 oacc[4] = {};
  int swz = (l15&7)<<4;

  // prologue: stage chunk 0
  u32x4 rk[2], rv[2];
  #pragma unroll
  for(int it=0; it<2; ++it){
    int cc = it*256 + tid;
    int r = cc>>3, cb = (cc&7)*16, scb = cb ^ ((r&7)<<4);
    rk[it] = *(const u32x4*)(Kpan + (u64)r*128u + scb);
    rv[it] = *(const u32x4*)(Vpan + (u64)r*1024u + scb);
  }
  #pragma unroll
  for(int it=0; it<2; ++it){
    int cc = it*256 + tid;
    int r = cc>>3, cb = (cc&7)*16;
    *(u32x4*)((char*)KL  + r*128 + cb) = rk[it];
    *(u32x4*)((char*)VtL + r*128 + cb) = rv[it];
  }
  __syncthreads();

  for(int c=0;c<8;++c){
    if(c < 7){
      // T14: issue next chunk's loads; hide under QK/softmax/PV
      #pragma unroll
      for(int it=0; it<2; ++it){
        int cc = it*256 + tid;
        int r = cc>>3, cb = (cc&7)*16, scb = cb ^ ((r&7)<<4);
        rk[it] = *(const u32x4*)(Kpan + (u64)((c+1)*64+r)*128u + scb);
        rv[it] = *(const u32x4*)(Vpan + (u64)r*1024u + (u64)(c+1)*128u + scb);
      }
    }
    // S^T = K * Q^T
    float sv[4][4];
    #pragma unroll
    for(int s=0;s<4;++s){
      int rk_ = (s*16 + l15)*128;
      s16x8 ka0 = *(const s16x8*)((const char*)KL + rk_ + ((g*16) ^ swz));
      s16x8 ka1 = *(const s16x8*)((const char*)KL + rk_ + ((64 + g*16) ^ swz));
      fx4 st = {0.f,0.f,0.f,0.f};
      st = mfma_16x16x32_bf16(ka0, qf0, st);
      st = mfma_16x16x32_bf16(ka1, qf1, st);
      fx4 mk = *(const fx4*)&mask_lds[c*64 + s*16 + g*4];
      #pragma unroll
      for(int q=0;q<4;++q) sv[s][q] = st[q]*scale + mk[q];
    }
    float cm = -3.0e38f;
    #pragma unroll
    for(int s=0;s<4;++s)
      #pragma unroll
      for(int q=0;q<4;++q) cm = fmaxf(cm, sv[s][q]);
    cm = fmaxf(cm, __shfl_xor(cm, 16, 64));
    cm = fmaxf(cm, __shfl_xor(cm, 32, 64));
    float m_new = fmaxf(m_run, cm);
    float alpha = __expf(m_run - m_new);
    float rs = 0.f;
    #pragma unroll
    for(int s=0;s<4;++s){
      #pragma unroll
      for(int q=0;q<4;++q){
        float e = __expf(sv[s][q] - m_new);
        rs += e;
        PT[wv][s*16 + g*4 + q][l15] = f2bf(e);
      }
    }
    rs += __shfl_xor(rs, 16, 64);
    rs += __shfl_xor(rs, 32, 64);
    l_run = l_run*alpha + rs;
    m_run = m_new;
    #pragma unroll
    for(int t=0;t<4;++t) oacc[t] *= alpha;
    asm volatile("s_waitcnt lgkmcnt(0)" ::: "memory");
    #pragma unroll
    for(int kh=0;kh<2;++kh){
      u16 ptmp[8];
      #pragma unroll
      for(int j=0;j<8;++j) ptmp[j] = PT[wv][kh*32 + g*8 + j][l15];
      s16x8 pbig; __builtin_memcpy(&pbig, ptmp, 16);
      #pragma unroll
      for(int t=0;t<4;++t){
        int rv_ = (t*16 + l15)*128;
        s16x8 va = *(const s16x8*)((const char*)VtL + rv_ + ((kh*64 + g*16) ^ swz));
        oacc[t] = mfma_16x16x32_bf16(va, pbig, oacc[t]);
      }
    }
    __syncthreads();
    if(c < 7){
      #pragma unroll
      for(int it=0; it<2; ++it){
        int cc = it*256 + tid;
        int r = cc>>3, cb = (cc&7)*16;
        *(u32x4*)((char*)KL  + r*128 + cb) = rk[it];
        *(u32x4*)((char*)VtL + r*128 + cb) = rv[it];
      }
      __syncthreads();
    }
  }

  // ---- epilogue: transpose numerator ONCE, then 8 p-corrections in registers ----
  #pragma unroll
  for(int t=0;t<4;++t)
    #pragma unroll
    for(int q=0;q<4;++q)
      obuf[wv][l15][t*16 + g*4 + q] = oacc[t][q];
  asm volatile("s_waitcnt lgkmcnt(0)" ::: "memory");

  int r = lane>>2, cbo = (lane&3)*16;
  fx4 N0 = *(const fx4*)&obuf[wv][r][cbo];
  fx4 N1 = *(const fx4*)&obuf[wv][r][cbo+4];
  fx4 N2 = *(const fx4*)&obuf[wv][r][cbo+8];
  fx4 N3 = *(const fx4*)&obuf[wv][r][cbo+12];
  float m_r = __shfl(m_run, r, 64);
  float l_r = __shfl(l_run, r, 64);
  float mke0 = mask_lds[512], mke1 = mask_lds[513];

  // Q2 chunk for this lane's row: dims cbo..cbo+15
  const u16* q2p = Q2e + ((u64)(b*16+h)*512u + q0 + r)*64u + cbo;
  float q2v[16];
  {
    s16x8 qa = *(const s16x8*)q2p;
    s16x8 qb2 = *(const s16x8*)(q2p+8);
    #pragma unroll
    for(int j=0;j<8;++j){ q2v[j]=bf2f((u16)qa[j]); q2v[8+j]=bf2f((u16)qb2[j]); }
  }

  for(int p=0;p<8;++p){
    const u16* KeP = Ke + ((u64)(b*8+p)*16u + h)*128u;
    float d0=0.f, d1=0.f;
    {
      const u16* k0p = KeP + cbo;
      const u16* k1p = KeP + 64 + cbo;
      s16x8 a0 = *(const s16x8*)k0p, a1 = *(const s16x8*)(k0p+8);
      s16x8 b0 = *(const s16x8*)k1p, b1 = *(const s16x8*)(k1p+8);
      #pragma unroll
      for(int j=0;j<8;++j){
        d0 += q2v[j]*bf2f((u16)a0[j]) + q2v[8+j]*bf2f((u16)a1[j]);
        d1 += q2v[j]*bf2f((u16)b0[j]) + q2v[8+j]*bf2f((u16)b1[j]);
      }
    }
    d0 += __shfl_xor(d0, 1, 64); d0 += __shfl_xor(d0, 2, 64);
    d1 += __shfl_xor(d1, 1, 64); d1 += __shfl_xor(d1, 2, 64);
    float s0 = d0*scale + mke0, s1 = d1*scale + mke1;
    float mp = fmaxf(m_r, fmaxf(s0, s1));
    float al = __expf(m_r - mp);
    float p0 = __expf(s0-mp), p1 = __expf(s1-mp);
    float linv = 1.0f/(l_r*al + p0 + p1);
    // Ve for dims cbo..cbo+15 (layout (...,d,e): interleaved)
    const u16* vep = VeT + ((u64)(b*8+p)*16u + h)*128u + cbo*2;
    u16 ve[32];
    {
      u32x4 w0 = *(const u32x4*)vep;
      u32x4 w1 = *(const u32x4*)(vep+8);
      u32x4 w2 = *(const u32x4*)(vep+16);
      u32x4 w3 = *(const u32x4*)(vep+24);
      __builtin_memcpy(ve,    &w0, 16);
      __builtin_memcpy(ve+8,  &w1, 16);
      __builtin_memcpy(ve+16, &w2, 16);
      __builtin_memcpy(ve+24, &w3, 16);
    }
    float o[16];
    #pragma unroll
    for(int j=0;j<4;++j){
      o[j]    = (N0[j]*al + p0*bf2f(ve[2*j])      + p1*bf2f(ve[2*j+1]))*linv;
      o[4+j]  = (N1[j]*al + p0*bf2f(ve[8+2*j])    + p1*bf2f(ve[8+2*j+1]))*linv;
      o[8+j]  = (N2[j]*al + p0*bf2f(ve[16+2*j])   + p1*bf2f(ve[16+2*j+1]))*linv;
      o[12+j] = (N3[j]*al + p0*bf2f(ve[24+2*j])   + p1*bf2f(ve[24+2*j+1]))*linv;
    }
    float* og = outw + ((u64)(b*8+p)*512u + q0 + r)*1024u + h*64 + cbo;
    *(fx4*)og      = *(const fx4*)&o[0];
    *(fx4*)(og+4)  = *(const fx4*)&o[4];
    *(fx4*)(og+8)  = *(const fx4*)&o[8];
    *(fx4*)(og+12) = *(const fx4*)&o[12];
  }
}

// ---------------- K3: entity-query rows (2 per (b,p,h)), simple VALU ----------------
__global__ __launch_bounds__(256) void k_ent_attn(
    const u16* __restrict__ Qe2w, const u16* __restrict__ Qe2e,
    const u16* __restrict__ Kw,   const u16* __restrict__ VwT,
    const u16* __restrict__ Ke,   const u16* __restrict__ VeT,
    const float* __restrict__ msk, float* __restrict__ oute)
{
  __shared__ float s_lds[2][516];
  __shared__ float qw_lds[2][64];
  __shared__ float qe_lds[2][64];
  __shared__ float red[2][8];
  int tid = threadIdx.x;
  int bid = blockIdx.x;
  int h = bid&15, p = (bid>>4)&7, b = bid>>7;
  u64 ebase = (u64)(b*8+p)*16u + h;
  if(tid < 128){
    int r = tid>>6, d = tid&63;
    qw_lds[r][d] = bf2f(Qe2w[(ebase*2 + r)*64 + d]);
    qe_lds[r][d] = bf2f(Qe2e[(ebase*2 + r)*64 + d]);
  }
  __syncthreads();
  const u16* Kpan = Kw + (u64)(b*16+h)*512u*64u;
  for(int k=tid;k<512;k+=256){
    const u16* kr = Kpan + (u64)k*64u;
    float d0=0.f, d1=0.f;
    #pragma unroll
    for(int j=0;j<64;j+=8){
      s16x8 kv = *(const s16x8*)(kr+j);
      #pragma unroll
      for(int x=0;x<8;++x){
        float kf = bf2f((u16)kv[x]);
        d0 += qw_lds[0][j+x]*kf;
        d1 += qw_lds[1][j+x]*kf;
      }
    }
    float mk = msk[b*514 + k];
    s_lds[0][k] = d0*0.125f + mk;
    s_lds[1][k] = d1*0.125f + mk;
  }
  if(tid < 4){
    int r = tid>>1, e = tid&1;
    const u16* kr = Ke + (ebase*2 + e)*64;
    float dd = 0.f;
    for(int j=0;j<64;++j) dd += qe_lds[r][j]*bf2f(kr[j]);
    s_lds[r][512+e] = dd*0.125f + msk[b*514 + 512 + e];
  }
  __syncthreads();
  float mx0=-3e38f, mx1=-3e38f;
  for(int k=tid;k<514;k+=256){ mx0=fmaxf(mx0,s_lds[0][k]); mx1=fmaxf(mx1,s_lds[1][k]); }
  #pragma unroll
  for(int off=32; off; off>>=1){
    mx0 = fmaxf(mx0, __shfl_xor(mx0, off, 64));
    mx1 = fmaxf(mx1, __shfl_xor(mx1, off, 64));
  }
  int wv = tid>>6, lane = tid&63;
  if(lane==0){ red[0][wv]=mx0; red[1][wv]=mx1; }
  __syncthreads();
  float m0 = fmaxf(fmaxf(red[0][0],red[0][1]),fmaxf(red[0][2],red[0][3]));
  float m1 = fmaxf(fmaxf(red[1][0],red[1][1]),fmaxf(red[1][2],red[1][3]));
  float sm0=0.f, sm1=0.f;
  for(int k=tid;k<514;k+=256){
    float e0 = __expf(s_lds[0][k]-m0); s_lds[0][k]=e0; sm0+=e0;
    float e1 = __expf(s_lds[1][k]-m1); s_lds[1][k]=e1; sm1+=e1;
  }
  #pragma unroll
  for(int off=32; off; off>>=1){
    sm0 += __shfl_xor(sm0, off, 64);
    sm1 += __shfl_xor(sm1, off, 64);
  }
  if(lane==0){ red[0][4+wv]=sm0; red[1][4+wv]=sm1; }
  __syncthreads();
  float l0 = red[0][4]+red[0][5]+red[0][6]+red[0][7];
  float l1 = red[1][4]+red[1][5]+red[1][6]+red[1][7];
  if(tid < 128){
    int r = tid>>6, d = tid&63;
    const u16* vr = VwT + ((u64)(b*16+h)*64u + d)*512u;
    float acc = 0.f;
    for(int k=0;k<512;k+=8){
      s16x8 vv = *(const s16x8*)(vr+k);
      #pragma unroll
      for(int x=0;x<8;++x) acc += s_lds[r][k+x]*bf2f((u16)vv[x]);
    }
    const u16* ve = VeT + (ebase*64 + d)*2;
    acc += s_lds[r][512]*bf2f(ve[0]) + s_lds[r][513]*bf2f(ve[1]);
    float val = acc / ((r==0)?l0:l1);
    oute[(((u64)(b*8+p)*2u + r)*1024u + h*64 + d)] = val;
  }
}

extern "C" void kernel_launch(void* const* d_in, const int* in_sizes, int n_in,
                              void* d_out, int out_size, void* d_ws, size_t ws_size,
                              hipStream_t stream)
{
  const float* words = (const float*)d_in[0];
  const float* ents  = (const float*)d_in[1];
  const float* amask = (const float*)d_in[2];
  const float* q_w   = (const float*)d_in[3];
  const float* q_b   = (const float*)d_in[4];
  const float* k_w   = (const float*)d_in[5];
  const float* k_b   = (const float*)d_in[6];
  const float* v_w   = (const float*)d_in[7];
  const float* v_b   = (const float*)d_in[8];
  const float* w2e_w = (const float*)d_in[9];
  const float* w2e_b = (const float*)d_in[10];
  const float* e2w_w = (const float*)d_in[11];
  const float* e2w_b = (const float*)d_in[12];
  const float* e2e_w = (const float*)d_in[13];
  const float* e2e_b = (const float*)d_in[14];

  const size_t MW = 1048576;   // u16 elements per 1024x1024 matrix
  u16* ws16 = (u16*)d_ws;
  if(ws_size < (11*MW + 5*32768)*sizeof(u16)) return;
  u16* WTq   = ws16 + 0*MW;
  u16* WTk   = ws16 + 1*MW;
  u16* WTv   = ws16 + 2*MW;
  u16* WTw2e = ws16 + 3*MW;
  u16* WTe2w = ws16 + 4*MW;
  u16* WTe2e = ws16 + 5*MW;
  u16* Qw    = ws16 + 6*MW;
  u16* Q2e   = ws16 + 7*MW;
  u16* Kwp   = ws16 + 8*MW;
  u16* VwTp  = ws16 + 9*MW;
  u16* Xbf   = ws16 + 10*MW;
  u16* Qe2w  = ws16 + 11*MW;
  u16* Qe2e  = Qe2w + 32768;
  u16* Kep   = Qe2e + 32768;
  u16* VeTp  = Kep + 32768;
  u16* Ebf   = VeTp + 32768;

  dim3 tb(256);
  k_prep<<<dim3(2064), tb, 0, stream>>>(q_w, k_w, v_w, w2e_w, e2w_w, e2e_w, ws16,
                                        words, Xbf, ents, Ebf);
  k_proj<<<dim3(8,9,4), tb, 0, stream>>>(Xbf, Ebf,
      WTq, WTw2e, WTk, WTv, WTe2w, WTe2e,
      q_b, w2e_b, k_b, v_b, e2w_b, e2e_b,
      Qw, Q2e, Kwp, VwTp, Qe2w, Qe2e, Kep, VeTp);
  k_word_attn<<<dim3(8,16,2), tb, 0, stream>>>(Qw, Q2e, Kwp, VwTp, Kep, VeTp, amask, (float*)d_out);
  k_ent_attn<<<dim3(256), tb, 0, stream>>>(Qe2w, Qe2e, Kwp, VwTp, Kep, VeTp, amask, (float*)d_out + 8388608u);
}

// Round 5
// 65.271 us; speedup vs baseline: 1.7469x; 1.1703x over previous
//
#include <hip/hip_runtime.h>
#include <hip/hip_bf16.h>

typedef __attribute__((ext_vector_type(8))) short s16x8;
typedef __attribute__((ext_vector_type(4))) float fx4;
typedef __attribute__((ext_vector_type(4))) unsigned int u32x4;
typedef unsigned short u16;
typedef unsigned int   u32;
typedef unsigned long long u64;

#define DI __device__ __forceinline__

// B=2, W=512, E=2, P=8, H=1024, NH=16, D=64, T=514
// External I/O: float32. Internal workspace: bf16 (MFMA).

DI float bf2f(u16 x){ u32 u = ((u32)x)<<16; float f; __builtin_memcpy(&f,&u,4); return f; }
DI u16 f2bf(float f){ u32 u; __builtin_memcpy(&u,&f,4); u = (u + 0x7fffu + ((u>>16)&1u))>>16; return (u16)u; }

DI fx4 mfma_16x16x32_bf16(s16x8 a, s16x8 b, fx4 c){
  return __builtin_amdgcn_mfma_f32_16x16x32_bf16(a,b,c,0,0,0);
}

// ---------------- K_prep: fused weight transpose (f32 k,n -> bf16 n,k) + activations cvt ----
__global__ __launch_bounds__(256) void k_prep(
    const float* __restrict__ s0, const float* __restrict__ s1, const float* __restrict__ s2,
    const float* __restrict__ s3, const float* __restrict__ s4, const float* __restrict__ s5,
    u16* __restrict__ dstbase,
    const float* __restrict__ words, u16* __restrict__ Xbf,
    const float* __restrict__ ents,  u16* __restrict__ Ebf)
{
  __shared__ __align__(16) u16 tile[64][72];
  int bx = blockIdx.x, tid = threadIdx.x;
  if(bx < 1536){
    int z = bx>>8, t = bx&255;
    const float* src = (z==0)?s0:(z==1)?s1:(z==2)?s2:(z==3)?s3:(z==4)?s4:s5;
    u16* dst = dstbase + (u64)z*1048576u;
    int kt = (t&15)*64, nt = (t>>4)*64;
    #pragma unroll
    for(int it=0; it<2; ++it){
      int c = it*256 + tid;
      int r = c>>3, col = (c&7)*8;
      const float* sp = src + (u64)(kt+r)*1024u + nt + col;
      fx4 a = *(const fx4*)sp;
      fx4 b = *(const fx4*)(sp+4);
      u16 o[8];
      o[0]=f2bf(a[0]); o[1]=f2bf(a[1]); o[2]=f2bf(a[2]); o[3]=f2bf(a[3]);
      o[4]=f2bf(b[0]); o[5]=f2bf(b[1]); o[6]=f2bf(b[2]); o[7]=f2bf(b[3]);
      __builtin_memcpy(&tile[r][col], o, 16);
    }
    __syncthreads();
    #pragma unroll
    for(int it=0; it<2; ++it){
      int c = it*256 + tid;
      int nr = c>>3, kc = (c&7)*8;
      u16 tmp[8];
      #pragma unroll
      for(int j=0;j<8;++j) tmp[j] = tile[kc+j][nr];
      u32x4 v; __builtin_memcpy(&v, tmp, 16);
      *(u32x4*)(dst + (u64)(nt+nr)*1024u + kt + kc) = v;
    }
  } else {
    const float* src; u16* dst; int i;
    if(bx < 2048){ src = words; dst = Xbf; i = ((bx-1536)*256 + tid)*8; }
    else         { src = ents;  dst = Ebf; i = ((bx-2048)*256 + tid)*8; }
    fx4 a = *(const fx4*)(src+i);
    fx4 b = *(const fx4*)(src+i+4);
    u16 o[8];
    o[0]=f2bf(a[0]); o[1]=f2bf(a[1]); o[2]=f2bf(a[2]); o[3]=f2bf(a[3]);
    o[4]=f2bf(b[0]); o[5]=f2bf(b[1]); o[6]=f2bf(b[2]); o[7]=f2bf(b[3]);
    u32x4 v; __builtin_memcpy(&v,o,16);
    *(u32x4*)(dst+i)=v;
  }
}

// ---------------- K_proj: all 8 projections in one launch ----------------
// grid (16, 9, 4): y<8 -> word GEMM, BM=128 BN=64 tile (2+ blocks/CU for wave overlap),
// T14 reg-prefetch. y==8 & x<8 -> entity GEMM (M=32, BN=128).
// word z: 0=Qw 1=Q2e 2=Kw 3=VwT ; ent z: 0=Qe2w 1=Qe2e 2=Ke 3=VeT
__global__ __launch_bounds__(256) void k_proj(
    const u16* __restrict__ Xbf, const u16* __restrict__ Ebf,
    const u16* __restrict__ wtq, const u16* __restrict__ wtw2e,
    const u16* __restrict__ wtk, const u16* __restrict__ wtv,
    const u16* __restrict__ wte2w, const u16* __restrict__ wte2e,
    const float* __restrict__ qb, const float* __restrict__ w2eb,
    const float* __restrict__ kb, const float* __restrict__ vb,
    const float* __restrict__ e2wb, const float* __restrict__ e2eb,
    u16* __restrict__ Qw, u16* __restrict__ Q2e, u16* __restrict__ Kwp, u16* __restrict__ VwTp,
    u16* __restrict__ Qe2w, u16* __restrict__ Qe2e, u16* __restrict__ Kep, u16* __restrict__ VeTp)
{
  __shared__ __align__(16) u16 XL[128*64];
  __shared__ __align__(16) u16 WL[128*64];   // word path uses first 64*64
  int tid = threadIdx.x;
  int z = blockIdx.z;
  int wv = tid>>6, lane = tid&63, l15 = lane&15, g = lane>>4;

  if(blockIdx.y < 8){
    // ---- word path: 128x64 output tile ----
    const u16* WT  = (z==0)?wtq:(z==1)?wtw2e:(z==2)?wtk:wtv;
    const float* bias = (z==0)?qb :(z==1)?w2eb :(z==2)?kb :vb;
    u16* out       = (z==0)?Qw :(z==1)?Q2e :(z==2)?Kwp :VwTp;
    int nt = blockIdx.x*64;
    int mt = blockIdx.y*128;
    int wr = (wv>>1)*64, wc = (wv&1)*32;
    fx4 acc[4][2] = {};
    u32x4 rx[4], rw[2];
    // prologue: K-tile 0
    #pragma unroll
    for(int it=0; it<4; ++it){
      int c = it*256 + tid;
      int r = c>>3, cb = (c&7)*16, scb = cb ^ ((r&7)<<4);
      rx[it] = *(const u32x4*)((const char*)Xbf + ((u64)(mt+r)*1024u)*2u + scb);
    }
    #pragma unroll
    for(int it=0; it<2; ++it){
      int c = it*256 + tid;
      int r = c>>3, cb = (c&7)*16, scb = cb ^ ((r&7)<<4);
      rw[it] = *(const u32x4*)((const char*)WT + ((u64)(nt+r)*1024u)*2u + scb);
    }
    #pragma unroll
    for(int it=0; it<4; ++it) *(u32x4*)((char*)XL + (it*256+tid)*16) = rx[it];
    #pragma unroll
    for(int it=0; it<2; ++it) *(u32x4*)((char*)WL + (it*256+tid)*16) = rw[it];
    __syncthreads();
    for(int t=0; t<16; ++t){
      int kn = (t+1)*64;
      if(t < 15){
        // T14: issue next tile's loads now; latency hides under MFMA below
        #pragma unroll
        for(int it=0; it<4; ++it){
          int c = it*256 + tid;
          int r = c>>3, cb = (c&7)*16, scb = cb ^ ((r&7)<<4);
          rx[it] = *(const u32x4*)((const char*)Xbf + ((u64)(mt+r)*1024u + kn)*2u + scb);
        }
        #pragma unroll
        for(int it=0; it<2; ++it){
          int c = it*256 + tid;
          int r = c>>3, cb = (c&7)*16, scb = cb ^ ((r&7)<<4);
          rw[it] = *(const u32x4*)((const char*)WT + ((u64)(nt+r)*1024u + kn)*2u + scb);
        }
      }
      #pragma unroll
      for(int ks=0; ks<2; ++ks){
        s16x8 af[4], bfv[2];
        #pragma unroll
        for(int i=0;i<4;++i){
          int ra = wr + i*16 + l15;
          af[i]  = *(const s16x8*)((const char*)XL + ra*128 + ((ks*64 + g*16) ^ ((ra&7)<<4)));
        }
        #pragma unroll
        for(int j=0;j<2;++j){
          int rb = wc + j*16 + l15;
          bfv[j] = *(const s16x8*)((const char*)WL + rb*128 + ((ks*64 + g*16) ^ ((rb&7)<<4)));
        }
        #pragma unroll
        for(int i=0;i<4;++i)
          #pragma unroll
          for(int j=0;j<2;++j)
            acc[i][j] = mfma_16x16x32_bf16(af[i], bfv[j], acc[i][j]);
      }
      __syncthreads();
      if(t < 15){
        #pragma unroll
        for(int it=0; it<4; ++it) *(u32x4*)((char*)XL + (it*256+tid)*16) = rx[it];
        #pragma unroll
        for(int it=0; it<2; ++it) *(u32x4*)((char*)WL + (it*256+tid)*16) = rw[it];
        __syncthreads();
      }
    }
    bool vmode = (z==3);
    #pragma unroll
    for(int j=0;j<2;++j){
      int n = nt + wc + j*16 + l15;
      float bv = bias[n];
      int h = n>>6, d = n&63;
      #pragma unroll
      for(int i=0;i<4;++i){
        #pragma unroll
        for(int q=0;q<4;++q){
          int m = mt + wr + i*16 + g*4 + q;
          int bb = m>>9, wrow = m&511;
          float v = acc[i][j][q] + bv;
          u64 o = vmode ? (((u64)(bb*16+h)*64u + d)*512u + wrow)
                        : (((u64)(bb*16+h)*512u + wrow)*64u + d);
          out[o] = f2bf(v);
        }
      }
    }
  } else {
    if(blockIdx.x >= 8) return;
    // ---- entity path (M=32, BN=128) ----
    const u16* WT  = (z==0)?wte2w:(z==1)?wte2e:(z==2)?wtk:wtv;
    const float* bias = (z==0)?e2wb :(z==1)?e2eb :(z==2)?kb :vb;
    u16* out       = (z==0)?Qe2w :(z==1)?Qe2e :(z==2)?Kep :VeTp;
    int nt = blockIdx.x*128;
    int wc = wv*32;
    fx4 acc[2][2] = {};
    for(int kk=0; kk<1024; kk+=64){
      {
        int r = tid>>3, cb = (tid&7)*16, scb = cb ^ ((r&7)<<4);
        *(u32x4*)((char*)XL + r*128 + cb) =
          *(const u32x4*)((const char*)Ebf + ((u64)r*1024u + kk)*2u + scb);
      }
      #pragma unroll
      for(int it=0; it<4; ++it){
        int c = it*256 + tid;
        int r = c>>3, cb = (c&7)*16, scb = cb ^ ((r&7)<<4);
        *(u32x4*)((char*)WL + r*128 + cb) =
          *(const u32x4*)((const char*)WT + ((u64)(nt+r)*1024u + kk)*2u + scb);
      }
      __syncthreads();
      #pragma unroll
      for(int ks=0; ks<2; ++ks){
        s16x8 af[2], bfv[2];
        #pragma unroll
        for(int i=0;i<2;++i){
          int ra = i*16 + l15;
          af[i]  = *(const s16x8*)((const char*)XL + ra*128 + ((ks*64 + g*16) ^ ((ra&7)<<4)));
          int rb = wc + i*16 + l15;
          bfv[i] = *(const s16x8*)((const char*)WL + rb*128 + ((ks*64 + g*16) ^ ((rb&7)<<4)));
        }
        #pragma unroll
        for(int i=0;i<2;++i)
          #pragma unroll
          for(int j=0;j<2;++j)
            acc[i][j] = mfma_16x16x32_bf16(af[i], bfv[j], acc[i][j]);
      }
      __syncthreads();
    }
    bool vmode = (z==3);
    #pragma unroll
    for(int j=0;j<2;++j){
      int n = nt + wc + j*16 + l15;
      float bv = bias[n];
      int h = n>>6, d = n&63;
      #pragma unroll
      for(int i=0;i<2;++i){
        #pragma unroll
        for(int q=0;q<4;++q){
          int m = i*16 + g*4 + q;     // 0..31 = ((b*8+p)*2+e)
          int bb = m>>4, p = (m>>1)&7, e = m&1;
          float v = acc[i][j][q] + bv;
          u64 base = ((u64)(bb*8+p)*16u + h);
          u64 o = vmode ? ((base*64u + d)*2u + e)
                        : ((base*2u + e)*64u + d);
          out[o] = f2bf(v);
        }
      }
    }
  }
}

// ---------------- K_attn: word-query flash attention + entity-query rows, one launch ----
// grid (16, 16, 2): x<8 -> word path (qc=x, h=y, b=z); x>=8 -> entity path (p=x-8, h=y, b=z).
__global__ __launch_bounds__(256) void k_attn(
    const u16* __restrict__ Qw,  const u16* __restrict__ Q2e,
    const u16* __restrict__ Kw,  const u16* __restrict__ VwT,
    const u16* __restrict__ Ke,  const u16* __restrict__ VeT,
    const u16* __restrict__ Qe2w, const u16* __restrict__ Qe2e,
    const float* __restrict__ msk, float* __restrict__ outw, float* __restrict__ oute)
{
  const float scale = 0.125f;
  __shared__ __align__(16) u16 KL[64*64];
  __shared__ __align__(16) u16 VtL[64*64];
  __shared__ __align__(16) u16 PT[4][64][18];
  __shared__ __align__(16) float mask_lds[576];
  __shared__ __align__(16) float obuf[4][16][68];
  __shared__ float s_lds[2][516];
  __shared__ float red[2][8];
  int tid = threadIdx.x;
  int h = blockIdx.y, b = blockIdx.z;
  int wv = tid>>6, lane = tid&63, l15 = lane&15, g = lane>>4;

  if(blockIdx.x < 8){
    // =================== word path ===================
    int qc = blockIdx.x;
    int q0 = qc*64 + wv*16;

    for(int i=tid;i<576;i+=256) mask_lds[i] = (i<514) ? msk[b*514+i] : 0.f;

    const u16* Qrow = Qw + ((u64)(b*16+h)*512u + q0 + l15)*64u;
    s16x8 qf0 = *(const s16x8*)(Qrow + g*8);
    s16x8 qf1 = *(const s16x8*)(Qrow + 32 + g*8);

    const char* Kpan = (const char*)(Kw  + (u64)(b*16+h)*512u*64u);
    const char* Vpan = (const char*)(VwT + (u64)(b*16+h)*64u*512u);

    float m_run = -3.0e38f, l_run = 0.f;
    fx4 oacc[4] = {};
    int swz = (l15&7)<<4;

    u32x4 rk[2], rv[2];
    #pragma unroll
    for(int it=0; it<2; ++it){
      int cc = it*256 + tid;
      int r = cc>>3, cb = (cc&7)*16, scb = cb ^ ((r&7)<<4);
      rk[it] = *(const u32x4*)(Kpan + (u64)r*128u + scb);
      rv[it] = *(const u32x4*)(Vpan + (u64)r*1024u + scb);
    }
    #pragma unroll
    for(int it=0; it<2; ++it){
      int cc = it*256 + tid;
      int r = cc>>3, cb = (cc&7)*16;
      *(u32x4*)((char*)KL  + r*128 + cb) = rk[it];
      *(u32x4*)((char*)VtL + r*128 + cb) = rv[it];
    }
    __syncthreads();

    for(int c=0;c<8;++c){
      if(c < 7){
        #pragma unroll
        for(int it=0; it<2; ++it){
          int cc = it*256 + tid;
          int r = cc>>3, cb = (cc&7)*16, scb = cb ^ ((r&7)<<4);
          rk[it] = *(const u32x4*)(Kpan + (u64)((c+1)*64+r)*128u + scb);
          rv[it] = *(const u32x4*)(Vpan + (u64)r*1024u + (u64)(c+1)*128u + scb);
        }
      }
      float sv[4][4];
      #pragma unroll
      for(int s=0;s<4;++s){
        int rk_ = (s*16 + l15)*128;
        s16x8 ka0 = *(const s16x8*)((const char*)KL + rk_ + ((g*16) ^ swz));
        s16x8 ka1 = *(const s16x8*)((const char*)KL + rk_ + ((64 + g*16) ^ swz));
        fx4 st = {0.f,0.f,0.f,0.f};
        st = mfma_16x16x32_bf16(ka0, qf0, st);
        st = mfma_16x16x32_bf16(ka1, qf1, st);
        fx4 mk = *(const fx4*)&mask_lds[c*64 + s*16 + g*4];
        #pragma unroll
        for(int q=0;q<4;++q) sv[s][q] = st[q]*scale + mk[q];
      }
      float cm = -3.0e38f;
      #pragma unroll
      for(int s=0;s<4;++s)
        #pragma unroll
        for(int q=0;q<4;++q) cm = fmaxf(cm, sv[s][q]);
      cm = fmaxf(cm, __shfl_xor(cm, 16, 64));
      cm = fmaxf(cm, __shfl_xor(cm, 32, 64));
      float m_new = fmaxf(m_run, cm);
      float alpha = __expf(m_run - m_new);
      float rs = 0.f;
      #pragma unroll
      for(int s=0;s<4;++s){
        #pragma unroll
        for(int q=0;q<4;++q){
          float e = __expf(sv[s][q] - m_new);
          rs += e;
          PT[wv][s*16 + g*4 + q][l15] = f2bf(e);
        }
      }
      rs += __shfl_xor(rs, 16, 64);
      rs += __shfl_xor(rs, 32, 64);
      l_run = l_run*alpha + rs;
      m_run = m_new;
      #pragma unroll
      for(int t=0;t<4;++t) oacc[t] *= alpha;
      asm volatile("s_waitcnt lgkmcnt(0)" ::: "memory");
      #pragma unroll
      for(int kh=0;kh<2;++kh){
        u16 ptmp[8];
        #pragma unroll
        for(int j=0;j<8;++j) ptmp[j] = PT[wv][kh*32 + g*8 + j][l15];
        s16x8 pbig; __builtin_memcpy(&pbig, ptmp, 16);
        #pragma unroll
        for(int t=0;t<4;++t){
          int rv_ = (t*16 + l15)*128;
          s16x8 va = *(const s16x8*)((const char*)VtL + rv_ + ((kh*64 + g*16) ^ swz));
          oacc[t] = mfma_16x16x32_bf16(va, pbig, oacc[t]);
        }
      }
      __syncthreads();
      if(c < 7){
        #pragma unroll
        for(int it=0; it<2; ++it){
          int cc = it*256 + tid;
          int r = cc>>3, cb = (cc&7)*16;
          *(u32x4*)((char*)KL  + r*128 + cb) = rk[it];
          *(u32x4*)((char*)VtL + r*128 + cb) = rv[it];
        }
        __syncthreads();
      }
    }

    // epilogue: transpose numerator once; 8 p-corrections in registers
    #pragma unroll
    for(int t=0;t<4;++t)
      #pragma unroll
      for(int q=0;q<4;++q)
        obuf[wv][l15][t*16 + g*4 + q] = oacc[t][q];
    asm volatile("s_waitcnt lgkmcnt(0)" ::: "memory");

    int r = lane>>2, cbo = (lane&3)*16;
    fx4 N0 = *(const fx4*)&obuf[wv][r][cbo];
    fx4 N1 = *(const fx4*)&obuf[wv][r][cbo+4];
    fx4 N2 = *(const fx4*)&obuf[wv][r][cbo+8];
    fx4 N3 = *(const fx4*)&obuf[wv][r][cbo+12];
    float m_r = __shfl(m_run, r, 64);
    float l_r = __shfl(l_run, r, 64);
    float mke0 = mask_lds[512], mke1 = mask_lds[513];

    const u16* q2p = Q2e + ((u64)(b*16+h)*512u + q0 + r)*64u + cbo;
    float q2v[16];
    {
      s16x8 qa = *(const s16x8*)q2p;
      s16x8 qb2 = *(const s16x8*)(q2p+8);
      #pragma unroll
      for(int j=0;j<8;++j){ q2v[j]=bf2f((u16)qa[j]); q2v[8+j]=bf2f((u16)qb2[j]); }
    }

    for(int p=0;p<8;++p){
      const u16* KeP = Ke + ((u64)(b*8+p)*16u + h)*128u;
      float d0=0.f, d1=0.f;
      {
        const u16* k0p = KeP + cbo;
        const u16* k1p = KeP + 64 + cbo;
        s16x8 a0 = *(const s16x8*)k0p, a1 = *(const s16x8*)(k0p+8);
        s16x8 b0 = *(const s16x8*)k1p, b1 = *(const s16x8*)(k1p+8);
        #pragma unroll
        for(int j=0;j<8;++j){
          d0 += q2v[j]*bf2f((u16)a0[j]) + q2v[8+j]*bf2f((u16)a1[j]);
          d1 += q2v[j]*bf2f((u16)b0[j]) + q2v[8+j]*bf2f((u16)b1[j]);
        }
      }
      d0 += __shfl_xor(d0, 1, 64); d0 += __shfl_xor(d0, 2, 64);
      d1 += __shfl_xor(d1, 1, 64); d1 += __shfl_xor(d1, 2, 64);
      float s0 = d0*scale + mke0, s1 = d1*scale + mke1;
      float mp = fmaxf(m_r, fmaxf(s0, s1));
      float al = __expf(m_r - mp);
      float p0 = __expf(s0-mp), p1 = __expf(s1-mp);
      float linv = 1.0f/(l_r*al + p0 + p1);
      const u16* vep = VeT + ((u64)(b*8+p)*16u + h)*128u + cbo*2;
      u16 ve[32];
      {
        u32x4 w0 = *(const u32x4*)vep;
        u32x4 w1 = *(const u32x4*)(vep+8);
        u32x4 w2 = *(const u32x4*)(vep+16);
        u32x4 w3 = *(const u32x4*)(vep+24);
        __builtin_memcpy(ve,    &w0, 16);
        __builtin_memcpy(ve+8,  &w1, 16);
        __builtin_memcpy(ve+16, &w2, 16);
        __builtin_memcpy(ve+24, &w3, 16);
      }
      float o[16];
      #pragma unroll
      for(int j=0;j<4;++j){
        o[j]    = (N0[j]*al + p0*bf2f(ve[2*j])      + p1*bf2f(ve[2*j+1]))*linv;
        o[4+j]  = (N1[j]*al + p0*bf2f(ve[8+2*j])    + p1*bf2f(ve[8+2*j+1]))*linv;
        o[8+j]  = (N2[j]*al + p0*bf2f(ve[16+2*j])   + p1*bf2f(ve[16+2*j+1]))*linv;
        o[12+j] = (N3[j]*al + p0*bf2f(ve[24+2*j])   + p1*bf2f(ve[24+2*j+1]))*linv;
      }
      float* og = outw + ((u64)(b*8+p)*512u + q0 + r)*1024u + h*64 + cbo;
      *(fx4*)og      = *(const fx4*)&o[0];
      *(fx4*)(og+4)  = *(const fx4*)&o[4];
      *(fx4*)(og+8)  = *(const fx4*)&o[8];
      *(fx4*)(og+12) = *(const fx4*)&o[12];
    }
  } else {
    // =================== entity path ===================
    int p = blockIdx.x - 8;
    u64 ebase = (u64)(b*8+p)*16u + h;
    float* qw_lds = (float*)KL;    // reuse LDS
    float* qe_lds = (float*)VtL;
    if(tid < 128){
      int r = tid>>6, d = tid&63;
      qw_lds[r*64+d] = bf2f(Qe2w[(ebase*2 + r)*64 + d]);
      qe_lds[r*64+d] = bf2f(Qe2e[(ebase*2 + r)*64 + d]);
    }
    __syncthreads();
    const u16* Kpan = Kw + (u64)(b*16+h)*512u*64u;
    for(int k=tid;k<512;k+=256){
      const u16* kr = Kpan + (u64)k*64u;
      float d0=0.f, d1=0.f;
      #pragma unroll
      for(int j=0;j<64;j+=8){
        s16x8 kv = *(const s16x8*)(kr+j);
        #pragma unroll
        for(int x=0;x<8;++x){
          float kf = bf2f((u16)kv[x]);
          d0 += qw_lds[j+x]*kf;
          d1 += qw_lds[64+j+x]*kf;
        }
      }
      float mk = msk[b*514 + k];
      s_lds[0][k] = d0*0.125f + mk;
      s_lds[1][k] = d1*0.125f + mk;
    }
    if(tid < 4){
      int r = tid>>1, e = tid&1;
      const u16* kr = Ke + (ebase*2 + e)*64;
      float dd = 0.f;
      for(int j=0;j<64;++j) dd += qe_lds[r*64+j]*bf2f(kr[j]);
      s_lds[r][512+e] = dd*0.125f + msk[b*514 + 512 + e];
    }
    __syncthreads();
    float mx0=-3e38f, mx1=-3e38f;
    for(int k=tid;k<514;k+=256){ mx0=fmaxf(mx0,s_lds[0][k]); mx1=fmaxf(mx1,s_lds[1][k]); }
    #pragma unroll
    for(int off=32; off; off>>=1){
      mx0 = fmaxf(mx0, __shfl_xor(mx0, off, 64));
      mx1 = fmaxf(mx1, __shfl_xor(mx1, off, 64));
    }
    if(lane==0){ red[0][wv]=mx0; red[1][wv]=mx1; }
    __syncthreads();
    float m0 = fmaxf(fmaxf(red[0][0],red[0][1]),fmaxf(red[0][2],red[0][3]));
    float m1 = fmaxf(fmaxf(red[1][0],red[1][1]),fmaxf(red[1][2],red[1][3]));
    float sm0=0.f, sm1=0.f;
    for(int k=tid;k<514;k+=256){
      float e0 = __expf(s_lds[0][k]-m0); s_lds[0][k]=e0; sm0+=e0;
      float e1 = __expf(s_lds[1][k]-m1); s_lds[1][k]=e1; sm1+=e1;
    }
    #pragma unroll
    for(int off=32; off; off>>=1){
      sm0 += __shfl_xor(sm0, off, 64);
      sm1 += __shfl_xor(sm1, off, 64);
    }
    if(lane==0){ red[0][4+wv]=sm0; red[1][4+wv]=sm1; }
    __syncthreads();
    float l0 = red[0][4]+red[0][5]+red[0][6]+red[0][7];
    float l1 = red[1][4]+red[1][5]+red[1][6]+red[1][7];
    if(tid < 128){
      int r = tid>>6, d = tid&63;
      const u16* vr = VwT + ((u64)(b*16+h)*64u + d)*512u;
      float acc = 0.f;
      for(int k=0;k<512;k+=8){
        s16x8 vv = *(const s16x8*)(vr+k);
        #pragma unroll
        for(int x=0;x<8;++x) acc += s_lds[r][k+x]*bf2f((u16)vv[x]);
      }
      const u16* ve = VeT + (ebase*64 + d)*2;
      acc += s_lds[r][512]*bf2f(ve[0]) + s_lds[r][513]*bf2f(ve[1]);
      float val = acc / ((r==0)?l0:l1);
      oute[(((u64)(b*8+p)*2u + r)*1024u + h*64 + d)] = val;
    }
  }
}

extern "C" void kernel_launch(void* const* d_in, const int* in_sizes, int n_in,
                              void* d_out, int out_size, void* d_ws, size_t ws_size,
                              hipStream_t stream)
{
  const float* words = (const float*)d_in[0];
  const float* ents  = (const float*)d_in[1];
  const float* amask = (const float*)d_in[2];
  const float* q_w   = (const float*)d_in[3];
  const float* q_b   = (const float*)d_in[4];
  const float* k_w   = (const float*)d_in[5];
  const float* k_b   = (const float*)d_in[6];
  const float* v_w   = (const float*)d_in[7];
  const float* v_b   = (const float*)d_in[8];
  const float* w2e_w = (const float*)d_in[9];
  const float* w2e_b = (const float*)d_in[10];
  const float* e2w_w = (const float*)d_in[11];
  const float* e2w_b = (const float*)d_in[12];
  const float* e2e_w = (const float*)d_in[13];
  const float* e2e_b = (const float*)d_in[14];

  const size_t MW = 1048576;   // u16 elements per 1024x1024 matrix
  u16* ws16 = (u16*)d_ws;
  if(ws_size < (11*MW + 5*32768)*sizeof(u16)) return;
  u16* WTq   = ws16 + 0*MW;
  u16* WTk   = ws16 + 1*MW;
  u16* WTv   = ws16 + 2*MW;
  u16* WTw2e = ws16 + 3*MW;
  u16* WTe2w = ws16 + 4*MW;
  u16* WTe2e = ws16 + 5*MW;
  u16* Qw    = ws16 + 6*MW;
  u16* Q2e   = ws16 + 7*MW;
  u16* Kwp   = ws16 + 8*MW;
  u16* VwTp  = ws16 + 9*MW;
  u16* Xbf   = ws16 + 10*MW;
  u16* Qe2w  = ws16 + 11*MW;
  u16* Qe2e  = Qe2w + 32768;
  u16* Kep   = Qe2e + 32768;
  u16* VeTp  = Kep + 32768;
  u16* Ebf   = VeTp + 32768;

  dim3 tb(256);
  k_prep<<<dim3(2064), tb, 0, stream>>>(q_w, k_w, v_w, w2e_w, e2w_w, e2e_w, ws16,
                                        words, Xbf, ents, Ebf);
  k_proj<<<dim3(16,9,4), tb, 0, stream>>>(Xbf, Ebf,
      WTq, WTw2e, WTk, WTv, WTe2w, WTe2e,
      q_b, w2e_b, k_b, v_b, e2w_b, e2e_b,
      Qw, Q2e, Kwp, VwTp, Qe2w, Qe2e, Kep, VeTp);
  k_attn<<<dim3(16,16,2), tb, 0, stream>>>(Qw, Q2e, Kwp, VwTp, Kep, VeTp,
      Qe2w, Qe2e, amask, (float*)d_out, (float*)d_out + 8388608u);
}